// Round 18
// baseline (107.592 us; speedup 1.0000x reference)
//
#include <hip/hip_runtime.h>
#include <stdint.h>

#define NB 4
#define LQ 2048
#define DM 512
#define NH 8
#define EH 64
#define MT (NB*LQ)   // 8192 rows
#define QBLK 128

typedef __attribute__((ext_vector_type(4)))  float f32x4;
typedef __attribute__((ext_vector_type(8)))  __bf16 bf16x8;
typedef __attribute__((ext_vector_type(8)))  unsigned short u16x8;
typedef __attribute__((ext_vector_type(4)))  short s16x4;
typedef __attribute__((ext_vector_type(4)))  float float4_t;
typedef __attribute__((ext_vector_type(2)))  unsigned int u32x2;
typedef __attribute__((ext_vector_type(4)))  unsigned int u32x4;

static __device__ __forceinline__ unsigned short f2bf(float f) {
  unsigned int u = __builtin_bit_cast(unsigned int, f);
  u += 0x7fffu + ((u >> 16) & 1u);   // RNE
  return (unsigned short)(u >> 16);
}

static __device__ __forceinline__ float bf2f(unsigned short h) {
  unsigned int u = ((unsigned int)h) << 16;
  return __builtin_bit_cast(float, u);
}

static __device__ __forceinline__ void gload16(const void* g, void* l) {
  __builtin_amdgcn_global_load_lds(
      (__attribute__((address_space(1))) unsigned int*)(g),
      (__attribute__((address_space(3))) unsigned int*)(l), 16, 0, 0);
}

static __device__ __forceinline__ unsigned int cvt_pk_bf16(float lo, float hi) {
  unsigned int r;
  asm("v_cvt_pk_bf16_f32 %0, %1, %2" : "=v"(r) : "v"(lo), "v"(hi));
  return r;
}

// 16x16x16 bf16 MFMA (K=16). Device-pass only (host sees a stub).
static __device__ __forceinline__ f32x4 mfma16(s16x4 a, s16x4 b, f32x4 c) {
#if defined(__HIP_DEVICE_COMPILE__)
#if __has_builtin(__builtin_amdgcn_mfma_f32_16x16x16bf16_1k)
  return __builtin_amdgcn_mfma_f32_16x16x16bf16_1k(a, b, c, 0, 0, 0);
#else
  f32x4 d;
  asm volatile("v_mfma_f32_16x16x16_bf16 %0, %1, %2, %3"
               : "=v"(d) : "v"(a), "v"(b), "0"(c));
  return d;
#endif
#else
  (void)a; (void)b;
  return c;
#endif
}

// ------------- cast + transpose weights: WT[z][n][k] = W[k][n] bf16 -------------
extern "C" __global__ __launch_bounds__(256) void k_cast_wt(
    const float* __restrict__ wq, const float* __restrict__ wk,
    const float* __restrict__ wv, const float* __restrict__ wo,
    unsigned short* __restrict__ wt) {
  __shared__ float tile[64][65];
  int z = blockIdx.z;
  const float* w = (z==0)?wq : (z==1)?wk : (z==2)?wv : wo;
  unsigned short* dst = wt + (size_t)z * DM * DM;
  int kb = blockIdx.y * 64, nb = blockIdx.x * 64;
  int t = threadIdx.x;
  int r = t >> 2, c0 = (t & 3) * 16;
  #pragma unroll
  for (int i = 0; i < 16; i += 4) {
    float4_t v4 = *(const float4_t*)(w + (size_t)(kb + r) * DM + nb + c0 + i);
    tile[r][c0+i]   = v4[0]; tile[r][c0+i+1] = v4[1];
    tile[r][c0+i+2] = v4[2]; tile[r][c0+i+3] = v4[3];
  }
  __syncthreads();
  u16x8 o0, o1;
  #pragma unroll
  for (int i = 0; i < 8; ++i) o0[i] = f2bf(tile[c0+i][r]);
  #pragma unroll
  for (int i = 0; i < 8; ++i) o1[i] = f2bf(tile[c0+8+i][r]);
  *(u16x8*)(dst + (size_t)(nb + r) * DM + kb + c0)     = o0;
  *(u16x8*)(dst + (size_t)(nb + r) * DM + kb + c0 + 8) = o1;
}

// ---- QKV GEMM with fused f32->bf16 A-cast; Q scaled by tau*log2e/8 ----
extern "C" __global__ __launch_bounds__(256) void k_gemm_qkv(
    const float* __restrict__ qin, const float* __restrict__ kin,
    const float* __restrict__ vin, const unsigned short* __restrict__ WT,
    const float* __restrict__ bq, const float* __restrict__ bk,
    const float* __restrict__ bv, const float* __restrict__ tau,
    unsigned short* __restrict__ out) {
  int bid = blockIdx.x;
  int wgid = (bid & 7) * 96 + (bid >> 3);
  int n0 = (wgid & 3) * 128;
  int p = wgid >> 2;              // 0..191
  int z = p % 3;
  int m0 = (p / 3) * 128;

  const float* Af = (z==0)?qin : (z==1)?kin : vin;
  const unsigned short* Bt = WT + (size_t)z * DM * DM;
  const float* bias = (z==0)?bq : (z==1)?bk : bv;
  unsigned short* dst = out + (size_t)z * MT * DM;

  __shared__ unsigned short As[2][128][32];
  __shared__ unsigned short Bs[2][128][32];

  float qsc = (z == 0) ? tau[m0 >> 11] * 0.18033688011112042f : 1.0f;
  int t = threadIdx.x;
  int lane = t & 63;
  int w = t >> 6;
  int wr = w >> 1, wc = w & 1;
  int g = lane >> 4, r15 = lane & 15;

  int ar = t >> 1, ah = t & 1;
  int as_ = (ar >> 1) & 3;
  int dlo = ((ah*2)     ^ as_) * 8;
  int dhi = ((ah*2 + 1) ^ as_) * 8;

  float4_t a0, a1, a2, a3;
  auto loadA = [&](int kt) {
    const float* src = Af + (size_t)(m0 + ar)*DM + kt*32 + ah*16;
    a0 = *(const float4_t*)(src);
    a1 = *(const float4_t*)(src + 4);
    a2 = *(const float4_t*)(src + 8);
    a3 = *(const float4_t*)(src + 12);
  };
  auto writeA = [&](int bb) {
    u32x4 lo, hi;
    lo[0] = cvt_pk_bf16(a0[0], a0[1]); lo[1] = cvt_pk_bf16(a0[2], a0[3]);
    lo[2] = cvt_pk_bf16(a1[0], a1[1]); lo[3] = cvt_pk_bf16(a1[2], a1[3]);
    hi[0] = cvt_pk_bf16(a2[0], a2[1]); hi[1] = cvt_pk_bf16(a2[2], a2[3]);
    hi[2] = cvt_pk_bf16(a3[0], a3[1]); hi[3] = cvt_pk_bf16(a3[2], a3[3]);
    *(u32x4*)(&As[bb][ar][dlo]) = lo;
    *(u32x4*)(&As[bb][ar][dhi]) = hi;
  };
  auto stageB = [&](int bb, int kt) {
    int k0 = kt * 32;
    int sblk = (t & 3) ^ ((t >> 3) & 3);
    #pragma unroll
    for (int j=0;j<2;j++) {
      int o = t*16 + j*4096;
      int row = o >> 6;
      gload16(Bt + (size_t)(n0+row)*DM + k0 + sblk*8, (char*)(&Bs[bb][0][0]) + o);
    }
  };

  f32x4 acc[4][4];
  #pragma unroll
  for (int i=0;i<4;i++)
    #pragma unroll
    for (int j=0;j<4;j++)
      #pragma unroll
      for (int e=0;e<4;e++) acc[i][j][e] = 0.f;

  loadA(0);
  writeA(0);
  stageB(0, 0);
  __syncthreads();
  int buf = 0;
  for (int kt = 0; kt < DM/32; ++kt) {
    bool pre = (kt + 1 < DM/32);
    if (pre) { loadA(kt + 1); stageB(buf ^ 1, kt + 1); }
    bf16x8 af[4], bfr[4];
    #pragma unroll
    for (int mi=0;mi<4;mi++) {
      int row = wr*64 + mi*16 + r15;
      int blk = g ^ ((row >> 1) & 3);
      af[mi] = *(const bf16x8*)(&As[buf][row][blk*8]);
    }
    #pragma unroll
    for (int ni=0;ni<4;ni++) {
      int row = wc*64 + ni*16 + r15;
      int blk = g ^ ((row >> 1) & 3);
      bfr[ni] = *(const bf16x8*)(&Bs[buf][row][blk*8]);
    }
    #pragma unroll
    for (int mi=0;mi<4;mi++)
      #pragma unroll
      for (int ni=0;ni<4;ni++)
        acc[mi][ni] = __builtin_amdgcn_mfma_f32_16x16x32_bf16(af[mi], bfr[ni], acc[mi][ni], 0, 0, 0);
    if (pre) writeA(buf ^ 1);
    __syncthreads();
    buf ^= 1;
  }
  #pragma unroll
  for (int ni=0;ni<4;ni++) {
    int n = n0 + wc*64 + ni*16 + r15;
    float bia = bias[n];
    int h = n >> 6, e = n & 63;
    #pragma unroll
    for (int mi=0;mi<4;mi++) {
      #pragma unroll
      for (int rg=0;rg<4;rg++) {
        int m = m0 + wr*64 + mi*16 + g*4 + rg;
        int b = m >> 11, s = m & 2047;
        dst[((size_t)((b*NH + h)*LQ + s))*EH + e] = f2bf((acc[mi][ni][rg] + bia) * qsc);
      }
    }
  }
}

// -------- V transpose, tile-interleaved + XOR-swizzled per 32-chunk --------
extern "C" __global__ __launch_bounds__(256) void k_vt(
    const unsigned short* __restrict__ qkv, unsigned short* __restrict__ vtg) {
  __shared__ unsigned short tile[64][65];   // [s_local][e]
  int bh = blockIdx.y;
  int s0 = blockIdx.x * 64;
  const unsigned short* Vh = qkv + (size_t)2*MT*DM + (size_t)bh*LQ*EH;
  unsigned short* Ot = vtg + (size_t)bh*EH*LQ;
  int t = threadIdx.x;
  int r = t >> 2, c0 = (t & 3) * 16;
  u16x8 a = *(const u16x8*)(Vh + (size_t)(s0 + r)*EH + c0);
  u16x8 b = *(const u16x8*)(Vh + (size_t)(s0 + r)*EH + c0 + 8);
  #pragma unroll
  for (int i=0;i<8;i++) { tile[r][c0+i] = a[i]; tile[r][c0+8+i] = b[i]; }
  __syncthreads();
  int gg = t & 3;
  int er = t >> 2;                      // e row 0..63
  int s2 = (er ^ (er >> 3)) & 3;
  #pragma unroll
  for (int blk = 0; blk < 2; ++blk) {
    u16x8 o;
    #pragma unroll
    for (int j = 0; j < 8; ++j) {
      int sp = blk*32 + (j >> 2)*16 + gg*4 + (j & 3);
      o[j] = tile[sp][er];
    }
    *(u16x8*)(Ot + (size_t)er*LQ + s0 + blk*32 + 8*(gg ^ s2)) = o;
  }
}

// -------- flash: 2-buffer, in-reg P via 16x16x16 PV; launch_bounds (256,5) --------
template<int NSPLIT>
__global__ __launch_bounds__(256, 5) void k_flash(
    const unsigned short* __restrict__ qkv, const unsigned short* __restrict__ vtg,
    unsigned short* __restrict__ aout,
    unsigned short* __restrict__ opart, float* __restrict__ lpart) {
  constexpr int SKV = LQ / NSPLIT;
  constexpr int NIT = SKV / 32;
  constexpr int CPX = (512 * NSPLIT) / 8;
  int bid = blockIdx.x;
  int wgid = (bid & 7) * CPX + (bid >> 3);   // bijective XCD chunk swizzle
  int part = wgid % NSPLIT;
  int rest = wgid / NSPLIT;
  int qblk = rest & 15;
  int bh = rest >> 4;
  int batch = bh >> 3, h = bh & 7;

  const unsigned short* Qh  = qkv + (size_t)bh * LQ * EH + (size_t)qblk * QBLK * EH;
  const unsigned short* Kh  = qkv + (size_t)MT * DM + (size_t)bh * LQ * EH + (size_t)part * SKV * EH;
  const unsigned short* VTh = vtg + (size_t)bh * EH * LQ + (size_t)part * SKV;

  __shared__ unsigned short Ks[2][32][64];    // 8KB
  __shared__ unsigned short Vt[2][64][32];    // 8KB

  int t = threadIdx.x;
  int lane = t & 63;
  int wv = t >> 6;
  int q4 = lane & 15;
  int g  = lane >> 4;

  auto stage = [&](int bb, int it) {
    int o = t * 16;
    int krow = t >> 3;
    int sblk = (t & 7) ^ ((krow ^ (krow >> 3)) & 7);
    gload16(Kh + (size_t)(it*32 + krow)*EH + sblk*8, (char*)(&Ks[bb][0][0]) + o);
    gload16(VTh + (size_t)(t >> 2)*LQ + it*32 + (t & 3)*8, (char*)(&Vt[bb][0][0]) + o);
  };

  // Q fragments direct from global (pre-scaled by tau*log2e/8)
  bf16x8 qf[2][2];
  #pragma unroll
  for (int qt=0;qt<2;qt++)
    #pragma unroll
    for (int st=0;st<2;st++)
      qf[qt][st] = *(const bf16x8*)(Qh + (size_t)(wv*32 + qt*16 + q4)*EH + st*32 + g*8);

  stage(0, 0);

  const f32x4 Z4 = {0.f, 0.f, 0.f, 0.f};
  f32x4 oacc[4][2];
  #pragma unroll
  for (int a=0;a<4;a++)
    #pragma unroll
    for (int b2=0;b2<2;b2++)
      #pragma unroll
      for (int e=0;e<4;e++) oacc[a][b2][e] = 0.f;
  float lsp[2] = {0.f, 0.f};

  __syncthreads();   // Ks[0], Vt[0] ready
  int buf = 0;
  for (int it = 0; it < NIT; ++it) {
    if (it + 1 < NIT) stage(buf ^ 1, it + 1);

    // QK^T: sac[kvt][qt], row = kv = kvt*16+g*4+reg, col = q = qt*16+q4
    f32x4 sac[2][2];
    __builtin_amdgcn_s_setprio(1);
    #pragma unroll
    for (int kvt=0; kvt<2; ++kvt) {
      int row = kvt*16 + q4;
      int S = (row ^ (row >> 3)) & 7;
      bf16x8 kf0 = *(const bf16x8*)(&Ks[buf][row][(g ^ S)*8]);
      sac[kvt][0] = __builtin_amdgcn_mfma_f32_16x16x32_bf16(kf0, qf[0][0], Z4, 0,0,0);
      sac[kvt][1] = __builtin_amdgcn_mfma_f32_16x16x32_bf16(kf0, qf[1][0], Z4, 0,0,0);
    }
    #pragma unroll
    for (int kvt=0; kvt<2; ++kvt) {
      int row = kvt*16 + q4;
      int S = (row ^ (row >> 3)) & 7;
      bf16x8 kf1 = *(const bf16x8*)(&Ks[buf][row][((4 + g) ^ S)*8]);
      sac[kvt][0] = __builtin_amdgcn_mfma_f32_16x16x32_bf16(kf1, qf[0][1], sac[kvt][0], 0,0,0);
      sac[kvt][1] = __builtin_amdgcn_mfma_f32_16x16x32_bf16(kf1, qf[1][1], sac[kvt][1], 0,0,0);
    }
    __builtin_amdgcn_s_setprio(0);

    // p = exp2(s) -> in-register 16x16x16 B-frags; per-lane ls partials
    s16x4 pk[2][2];   // [qt][kvt]
    #pragma unroll
    for (int qt=0; qt<2; ++qt) {
      #pragma unroll
      for (int kvt=0; kvt<2; ++kvt) {
        float p0 = __builtin_amdgcn_exp2f(sac[kvt][qt][0]);
        float p1 = __builtin_amdgcn_exp2f(sac[kvt][qt][1]);
        float p2 = __builtin_amdgcn_exp2f(sac[kvt][qt][2]);
        float p3 = __builtin_amdgcn_exp2f(sac[kvt][qt][3]);
        lsp[qt] += (p0 + p1) + (p2 + p3);
        union { u32x2 u; s16x4 h; } pu;
        pu.u[0] = cvt_pk_bf16(p0, p1);
        pu.u[1] = cvt_pk_bf16(p2, p3);
        pk[qt][kvt] = pu.h;
      }
    }

    // PV: out^T += V^T * P^T, two K=16 steps, P never leaves registers
    __builtin_amdgcn_s_setprio(1);
    #pragma unroll
    for (int et=0; et<4; ++et) {
      int row = et*16 + q4;
      int s2 = (row ^ (row >> 3)) & 3;
      union { u16x8 w; s16x4 h[2]; } vu;
      vu.w = *(const u16x8*)(&Vt[buf][row][(g ^ s2)*8]);
      oacc[et][0] = mfma16(vu.h[0], pk[0][0], oacc[et][0]);
      oacc[et][0] = mfma16(vu.h[1], pk[0][1], oacc[et][0]);
      oacc[et][1] = mfma16(vu.h[0], pk[1][0], oacc[et][1]);
      oacc[et][1] = mfma16(vu.h[1], pk[1][1], oacc[et][1]);
    }
    __builtin_amdgcn_s_setprio(0);

    __syncthreads();   // drain next-tile DMA + guard dbuf
    buf ^= 1;
  }

  // epilogue: reduce ls across lane groups, write partials / output
  #pragma unroll
  for (int qt=0; qt<2; ++qt) {
    float s = lsp[qt];
    s += __shfl_xor(s, 16, 64);
    s += __shfl_xor(s, 32, 64);
    int q = qblk*QBLK + wv*32 + qt*16 + q4;
    if constexpr (NSPLIT == 1) {
      float inv = 1.f / s;
      unsigned short* rowp = aout + (size_t)(batch*LQ + q)*DM + h*EH;
      #pragma unroll
      for (int et=0; et<4; ++et) {
        #pragma unroll
        for (int rg=0; rg<4; rg+=2) {
          int e = et*16 + g*4 + rg;
          *(unsigned int*)(rowp + e) = cvt_pk_bf16(oacc[et][qt][rg] * inv, oacc[et][qt][rg+1] * inv);
        }
      }
    } else {
      size_t r = (size_t)bh * LQ + q;
      unsigned short* od = opart + ((size_t)r*NSPLIT + part) * 64;
      #pragma unroll
      for (int et=0; et<4; ++et) {
        u32x2 wpk;
        wpk[0] = cvt_pk_bf16(oacc[et][qt][0], oacc[et][qt][1]);
        wpk[1] = cvt_pk_bf16(oacc[et][qt][2], oacc[et][qt][3]);
        *(u32x2*)(od + et*16 + g*4) = wpk;
      }
      if (g == 0) lpart[r*NSPLIT + part] = s;
    }
  }
}

// ---------------- combine split-S partials (bf16) -> bf16 AOut ----------------
extern "C" __global__ __launch_bounds__(256) void k_red(
    const unsigned short* __restrict__ op, const float* __restrict__ lp,
    unsigned short* __restrict__ aout) {
  int t = threadIdx.x;
  int r = blockIdx.x * 16 + (t >> 4);
  int e0 = (t & 15) * 4;
  float acc0 = 0.f, acc1 = 0.f, acc2 = 0.f, acc3 = 0.f, ls = 0.f;
  #pragma unroll
  for (int qq = 0; qq < 4; ++qq) {
    u32x2 wv = *(const u32x2*)(op + ((size_t)r*4 + qq)*64 + e0);
    acc0 += bf2f((unsigned short)(wv[0] & 0xFFFF));
    acc1 += bf2f((unsigned short)(wv[0] >> 16));
    acc2 += bf2f((unsigned short)(wv[1] & 0xFFFF));
    acc3 += bf2f((unsigned short)(wv[1] >> 16));
    ls += lp[(size_t)r*4 + qq];
  }
  float inv = 1.f / ls;
  int bh = r >> 11, q = r & 2047, batch = bh >> 3, h = bh & 7;
  unsigned short* dst = aout + (size_t)(batch*LQ + q)*DM + h*EH + e0;
  u32x2 w;
  w[0] = cvt_pk_bf16(acc0 * inv, acc1 * inv);
  w[1] = cvt_pk_bf16(acc2 * inv, acc3 * inv);
  *(u32x2*)dst = w;
}

// ---- output projection GEMM, 64x128 tile, grid 512 = 2 blocks/CU -> f32 ----
extern "C" __global__ __launch_bounds__(256) void k_gemm_out(
    const unsigned short* __restrict__ A, const unsigned short* __restrict__ WT,
    const float* __restrict__ bo, float* __restrict__ out) {
  const unsigned short* Bt = WT + (size_t)3 * DM * DM;

  __shared__ unsigned short As[2][64][32];    // 8KB
  __shared__ unsigned short Bs[2][128][32];   // 16KB

  int bid = blockIdx.x;
  int wgid = (bid & 7) * 64 + (bid >> 3);     // XCD swizzle over 512 blocks
  int n0 = (wgid & 3) * 128;
  int m0 = (wgid >> 2) * 64;

  int t = threadIdx.x;
  int lane = t & 63;
  int w = t >> 6;                             // wave owns n-slice w*32
  int g = lane >> 4, r15 = lane & 15;

  f32x4 acc[4][2];
  #pragma unroll
  for (int i=0;i<4;i++)
    #pragma unroll
    for (int j=0;j<2;j++)
      #pragma unroll
      for (int e=0;e<4;e++) acc[i][j][e] = 0.f;

  auto stage = [&](int bb, int kt) {
    int k0 = kt * 32;
    int sblk = (t & 3) ^ ((t >> 3) & 3);
    {   // A: 64 rows, one 16B load/thread; row = t>>2, (t>>3)&3 == (row>>1)&3
      int o = t * 16;
      int row = o >> 6;
      gload16(A + (size_t)(m0+row)*DM + k0 + sblk*8, (char*)(&As[bb][0][0]) + o);
    }
    #pragma unroll
    for (int j=0;j<2;j++) {   // B: 128 rows
      int o = t*16 + j*4096;
      int row = o >> 6;
      gload16(Bt + (size_t)(n0+row)*DM + k0 + sblk*8, (char*)(&Bs[bb][0][0]) + o);
    }
  };

  stage(0, 0);
  __syncthreads();
  int buf = 0;
  for (int kt = 0; kt < DM/32; ++kt) {
    if (kt + 1 < DM/32) stage(buf ^ 1, kt + 1);
    bf16x8 af[4], bfr[2];
    #pragma unroll
    for (int mi=0;mi<4;mi++) {
      int row = mi*16 + r15;
      int blk = g ^ ((row >> 1) & 3);
      af[mi] = *(const bf16x8*)(&As[buf][row][blk*8]);
    }
    #pragma unroll
    for (int ni=0;ni<2;ni++) {
      int row = w*32 + ni*16 + r15;
      int blk = g ^ ((row >> 1) & 3);
      bfr[ni] = *(const bf16x8*)(&Bs[buf][row][blk*8]);
    }
    #pragma unroll
    for (int mi=0;mi<4;mi++)
      #pragma unroll
      for (int ni=0;ni<2;ni++)
        acc[mi][ni] = __builtin_amdgcn_mfma_f32_16x16x32_bf16(af[mi], bfr[ni], acc[mi][ni], 0, 0, 0);
    __syncthreads();
    buf ^= 1;
  }
  #pragma unroll
  for (int ni=0;ni<2;ni++) {
    int n = n0 + w*32 + ni*16 + r15;
    float bia = bo[n];
    #pragma unroll
    for (int mi=0;mi<4;mi++) {
      #pragma unroll
      for (int rg=0;rg<4;rg++) {
        int m = m0 + mi*16 + g*4 + rg;
        out[(size_t)m*DM + n] = acc[mi][ni][rg] + bia;
      }
    }
  }
}

extern "C" void kernel_launch(void* const* d_in, const int* in_sizes, int n_in,
                              void* d_out, int out_size, void* d_ws, size_t ws_size,
                              hipStream_t stream) {
  const float* queries = (const float*)d_in[0];
  const float* keys    = (const float*)d_in[1];
  const float* values  = (const float*)d_in[2];
  const float* tau     = (const float*)d_in[3];
  // d_in[4] = delta : cancels in softmax -> unused
  const float* Wq = (const float*)d_in[5];
  const float* bq = (const float*)d_in[6];
  const float* Wk = (const float*)d_in[7];
  const float* bk = (const float*)d_in[8];
  const float* Wv = (const float*)d_in[9];
  const float* bv = (const float*)d_in[10];
  const float* Wo = (const float*)d_in[11];
  const float* bo = (const float*)d_in[12];
  float* out = (float*)d_out;

  char* ws = (char*)d_ws;
  unsigned short* WT   = (unsigned short*)(ws);                  // 2 MB  @0
  unsigned short* VTg  = (unsigned short*)(ws + (2u  << 20));    // 8 MB  @2
  unsigned short* AOut = (unsigned short*)(ws + (10u << 20));    // 8 MB  @10
  unsigned short* QKV  = (unsigned short*)(ws + (26u << 20));    // 24 MB @26
  unsigned short* Opart= (unsigned short*)(ws + (50u << 20));    // 33.6 MB @50 (bf16)
  float*          Lpart= (float*)(ws + (84u << 20));             // 1 MB  @84

  k_cast_wt <<<dim3(8, 8, 4), dim3(256), 0, stream>>>(Wq, Wk, Wv, Wo, WT);
  k_gemm_qkv<<<dim3(768), dim3(256), 0, stream>>>(queries, keys, values, WT,
                                                  bq, bk, bv, tau, QKV);
  k_vt      <<<dim3(32, 32), dim3(256), 0, stream>>>(QKV, VTg);

  if (ws_size >= ((size_t)85u << 20)) {
    k_flash<4><<<dim3(2048), dim3(256), 0, stream>>>(QKV, VTg, AOut, Opart, Lpart);
    k_red     <<<dim3(4096), dim3(256), 0, stream>>>(Opart, Lpart, AOut);
  } else {
    k_flash<1><<<dim3(512), dim3(256), 0, stream>>>(QKV, VTg, AOut, Opart, Lpart);
  }
  k_gemm_out<<<dim3(512), dim3(256), 0, stream>>>(AOut, WT, bo, out);
}

// Round 19
// 106.273 us; speedup vs baseline: 1.0124x; 1.0124x over previous
//
#include <hip/hip_runtime.h>
#include <stdint.h>

#define NB 4
#define LQ 2048
#define DM 512
#define NH 8
#define EH 64
#define MT (NB*LQ)   // 8192 rows
#define QBLK 128

typedef __attribute__((ext_vector_type(4)))  float f32x4;
typedef __attribute__((ext_vector_type(8)))  __bf16 bf16x8;
typedef __attribute__((ext_vector_type(8)))  unsigned short u16x8;
typedef __attribute__((ext_vector_type(4)))  short s16x4;
typedef __attribute__((ext_vector_type(4)))  float float4_t;
typedef __attribute__((ext_vector_type(2)))  unsigned int u32x2;
typedef __attribute__((ext_vector_type(4)))  unsigned int u32x4;

static __device__ __forceinline__ unsigned short f2bf(float f) {
  unsigned int u = __builtin_bit_cast(unsigned int, f);
  u += 0x7fffu + ((u >> 16) & 1u);   // RNE
  return (unsigned short)(u >> 16);
}

static __device__ __forceinline__ float bf2f(unsigned short h) {
  unsigned int u = ((unsigned int)h) << 16;
  return __builtin_bit_cast(float, u);
}

static __device__ __forceinline__ void gload16(const void* g, void* l) {
  __builtin_amdgcn_global_load_lds(
      (__attribute__((address_space(1))) unsigned int*)(g),
      (__attribute__((address_space(3))) unsigned int*)(l), 16, 0, 0);
}

static __device__ __forceinline__ unsigned int cvt_pk_bf16(float lo, float hi) {
  unsigned int r;
  asm("v_cvt_pk_bf16_f32 %0, %1, %2" : "=v"(r) : "v"(lo), "v"(hi));
  return r;
}

// 16x16x16 bf16 MFMA (K=16). Device-pass only (host sees a stub).
static __device__ __forceinline__ f32x4 mfma16(s16x4 a, s16x4 b, f32x4 c) {
#if defined(__HIP_DEVICE_COMPILE__)
#if __has_builtin(__builtin_amdgcn_mfma_f32_16x16x16bf16_1k)
  return __builtin_amdgcn_mfma_f32_16x16x16bf16_1k(a, b, c, 0, 0, 0);
#else
  f32x4 d;
  asm volatile("v_mfma_f32_16x16x16_bf16 %0, %1, %2, %3"
               : "=v"(d) : "v"(a), "v"(b), "0"(c));
  return d;
#endif
#else
  (void)a; (void)b;
  return c;
#endif
}

// ------------- cast + transpose weights: WT[z][n][k] = W[k][n] bf16 -------------
extern "C" __global__ __launch_bounds__(256) void k_cast_wt(
    const float* __restrict__ wq, const float* __restrict__ wk,
    const float* __restrict__ wv, const float* __restrict__ wo,
    unsigned short* __restrict__ wt) {
  __shared__ float tile[64][65];
  int z = blockIdx.z;
  const float* w = (z==0)?wq : (z==1)?wk : (z==2)?wv : wo;
  unsigned short* dst = wt + (size_t)z * DM * DM;
  int kb = blockIdx.y * 64, nb = blockIdx.x * 64;
  int t = threadIdx.x;
  int r = t >> 2, c0 = (t & 3) * 16;
  #pragma unroll
  for (int i = 0; i < 16; i += 4) {
    float4_t v4 = *(const float4_t*)(w + (size_t)(kb + r) * DM + nb + c0 + i);
    tile[r][c0+i]   = v4[0]; tile[r][c0+i+1] = v4[1];
    tile[r][c0+i+2] = v4[2]; tile[r][c0+i+3] = v4[3];
  }
  __syncthreads();
  u16x8 o0, o1;
  #pragma unroll
  for (int i = 0; i < 8; ++i) o0[i] = f2bf(tile[c0+i][r]);
  #pragma unroll
  for (int i = 0; i < 8; ++i) o1[i] = f2bf(tile[c0+8+i][r]);
  *(u16x8*)(dst + (size_t)(nb + r) * DM + kb + c0)     = o0;
  *(u16x8*)(dst + (size_t)(nb + r) * DM + kb + c0 + 8) = o1;
}

// ---- QKV GEMM with fused f32->bf16 A-cast; Q scaled by tau*log2e/8 ----
extern "C" __global__ __launch_bounds__(256) void k_gemm_qkv(
    const float* __restrict__ qin, const float* __restrict__ kin,
    const float* __restrict__ vin, const unsigned short* __restrict__ WT,
    const float* __restrict__ bq, const float* __restrict__ bk,
    const float* __restrict__ bv, const float* __restrict__ tau,
    unsigned short* __restrict__ out) {
  int bid = blockIdx.x;
  int wgid = (bid & 7) * 96 + (bid >> 3);
  int n0 = (wgid & 3) * 128;
  int p = wgid >> 2;              // 0..191
  int z = p % 3;
  int m0 = (p / 3) * 128;

  const float* Af = (z==0)?qin : (z==1)?kin : vin;
  const unsigned short* Bt = WT + (size_t)z * DM * DM;
  const float* bias = (z==0)?bq : (z==1)?bk : bv;
  unsigned short* dst = out + (size_t)z * MT * DM;

  __shared__ unsigned short As[2][128][32];
  __shared__ unsigned short Bs[2][128][32];

  float qsc = (z == 0) ? tau[m0 >> 11] * 0.18033688011112042f : 1.0f;
  int t = threadIdx.x;
  int lane = t & 63;
  int w = t >> 6;
  int wr = w >> 1, wc = w & 1;
  int g = lane >> 4, r15 = lane & 15;

  int ar = t >> 1, ah = t & 1;
  int as_ = (ar >> 1) & 3;
  int dlo = ((ah*2)     ^ as_) * 8;
  int dhi = ((ah*2 + 1) ^ as_) * 8;

  float4_t a0, a1, a2, a3;
  auto loadA = [&](int kt) {
    const float* src = Af + (size_t)(m0 + ar)*DM + kt*32 + ah*16;
    a0 = *(const float4_t*)(src);
    a1 = *(const float4_t*)(src + 4);
    a2 = *(const float4_t*)(src + 8);
    a3 = *(const float4_t*)(src + 12);
  };
  auto writeA = [&](int bb) {
    u32x4 lo, hi;
    lo[0] = cvt_pk_bf16(a0[0], a0[1]); lo[1] = cvt_pk_bf16(a0[2], a0[3]);
    lo[2] = cvt_pk_bf16(a1[0], a1[1]); lo[3] = cvt_pk_bf16(a1[2], a1[3]);
    hi[0] = cvt_pk_bf16(a2[0], a2[1]); hi[1] = cvt_pk_bf16(a2[2], a2[3]);
    hi[2] = cvt_pk_bf16(a3[0], a3[1]); hi[3] = cvt_pk_bf16(a3[2], a3[3]);
    *(u32x4*)(&As[bb][ar][dlo]) = lo;
    *(u32x4*)(&As[bb][ar][dhi]) = hi;
  };
  auto stageB = [&](int bb, int kt) {
    int k0 = kt * 32;
    int sblk = (t & 3) ^ ((t >> 3) & 3);
    #pragma unroll
    for (int j=0;j<2;j++) {
      int o = t*16 + j*4096;
      int row = o >> 6;
      gload16(Bt + (size_t)(n0+row)*DM + k0 + sblk*8, (char*)(&Bs[bb][0][0]) + o);
    }
  };

  f32x4 acc[4][4];
  #pragma unroll
  for (int i=0;i<4;i++)
    #pragma unroll
    for (int j=0;j<4;j++)
      #pragma unroll
      for (int e=0;e<4;e++) acc[i][j][e] = 0.f;

  loadA(0);
  writeA(0);
  stageB(0, 0);
  __syncthreads();
  int buf = 0;
  for (int kt = 0; kt < DM/32; ++kt) {
    bool pre = (kt + 1 < DM/32);
    if (pre) { loadA(kt + 1); stageB(buf ^ 1, kt + 1); }
    bf16x8 af[4], bfr[4];
    #pragma unroll
    for (int mi=0;mi<4;mi++) {
      int row = wr*64 + mi*16 + r15;
      int blk = g ^ ((row >> 1) & 3);
      af[mi] = *(const bf16x8*)(&As[buf][row][blk*8]);
    }
    #pragma unroll
    for (int ni=0;ni<4;ni++) {
      int row = wc*64 + ni*16 + r15;
      int blk = g ^ ((row >> 1) & 3);
      bfr[ni] = *(const bf16x8*)(&Bs[buf][row][blk*8]);
    }
    #pragma unroll
    for (int mi=0;mi<4;mi++)
      #pragma unroll
      for (int ni=0;ni<4;ni++)
        acc[mi][ni] = __builtin_amdgcn_mfma_f32_16x16x32_bf16(af[mi], bfr[ni], acc[mi][ni], 0, 0, 0);
    if (pre) writeA(buf ^ 1);
    __syncthreads();
    buf ^= 1;
  }
  #pragma unroll
  for (int ni=0;ni<4;ni++) {
    int n = n0 + wc*64 + ni*16 + r15;
    float bia = bias[n];
    int h = n >> 6, e = n & 63;
    #pragma unroll
    for (int mi=0;mi<4;mi++) {
      #pragma unroll
      for (int rg=0;rg<4;rg++) {
        int m = m0 + wr*64 + mi*16 + g*4 + rg;
        int b = m >> 11, s = m & 2047;
        dst[((size_t)((b*NH + h)*LQ + s))*EH + e] = f2bf((acc[mi][ni][rg] + bia) * qsc);
      }
    }
  }
}

// -------- V transpose, tile-interleaved + XOR-swizzled per 32-chunk --------
extern "C" __global__ __launch_bounds__(256) void k_vt(
    const unsigned short* __restrict__ qkv, unsigned short* __restrict__ vtg) {
  __shared__ unsigned short tile[64][65];   // [s_local][e]
  int bh = blockIdx.y;
  int s0 = blockIdx.x * 64;
  const unsigned short* Vh = qkv + (size_t)2*MT*DM + (size_t)bh*LQ*EH;
  unsigned short* Ot = vtg + (size_t)bh*EH*LQ;
  int t = threadIdx.x;
  int r = t >> 2, c0 = (t & 3) * 16;
  u16x8 a = *(const u16x8*)(Vh + (size_t)(s0 + r)*EH + c0);
  u16x8 b = *(const u16x8*)(Vh + (size_t)(s0 + r)*EH + c0 + 8);
  #pragma unroll
  for (int i=0;i<8;i++) { tile[r][c0+i] = a[i]; tile[r][c0+8+i] = b[i]; }
  __syncthreads();
  int gg = t & 3;
  int er = t >> 2;                      // e row 0..63
  int s2 = (er ^ (er >> 3)) & 3;
  #pragma unroll
  for (int blk = 0; blk < 2; ++blk) {
    u16x8 o;
    #pragma unroll
    for (int j = 0; j < 8; ++j) {
      int sp = blk*32 + (j >> 2)*16 + gg*4 + (j & 3);
      o[j] = tile[sp][er];
    }
    *(u16x8*)(Ot + (size_t)er*LQ + s0 + blk*32 + 8*(gg ^ s2)) = o;
  }
}

// -------- flash: 2-buffer, in-reg P via 16x16x16 PV; launch_bounds (256,5) --------
template<int NSPLIT>
__global__ __launch_bounds__(256, 5) void k_flash(
    const unsigned short* __restrict__ qkv, const unsigned short* __restrict__ vtg,
    unsigned short* __restrict__ aout,
    unsigned short* __restrict__ opart, float* __restrict__ lpart) {
  constexpr int SKV = LQ / NSPLIT;
  constexpr int NIT = SKV / 32;
  constexpr int CPX = (512 * NSPLIT) / 8;
  int bid = blockIdx.x;
  int wgid = (bid & 7) * CPX + (bid >> 3);   // bijective XCD chunk swizzle
  int part = wgid % NSPLIT;
  int rest = wgid / NSPLIT;
  int qblk = rest & 15;
  int bh = rest >> 4;
  int batch = bh >> 3, h = bh & 7;

  const unsigned short* Qh  = qkv + (size_t)bh * LQ * EH + (size_t)qblk * QBLK * EH;
  const unsigned short* Kh  = qkv + (size_t)MT * DM + (size_t)bh * LQ * EH + (size_t)part * SKV * EH;
  const unsigned short* VTh = vtg + (size_t)bh * EH * LQ + (size_t)part * SKV;

  __shared__ unsigned short Ks[2][32][64];    // 8KB
  __shared__ unsigned short Vt[2][64][32];    // 8KB

  int t = threadIdx.x;
  int lane = t & 63;
  int wv = t >> 6;
  int q4 = lane & 15;
  int g  = lane >> 4;

  auto stage = [&](int bb, int it) {
    int o = t * 16;
    int krow = t >> 3;
    int sblk = (t & 7) ^ ((krow ^ (krow >> 3)) & 7);
    gload16(Kh + (size_t)(it*32 + krow)*EH + sblk*8, (char*)(&Ks[bb][0][0]) + o);
    gload16(VTh + (size_t)(t >> 2)*LQ + it*32 + (t & 3)*8, (char*)(&Vt[bb][0][0]) + o);
  };

  // Q fragments direct from global (pre-scaled by tau*log2e/8)
  bf16x8 qf[2][2];
  #pragma unroll
  for (int qt=0;qt<2;qt++)
    #pragma unroll
    for (int st=0;st<2;st++)
      qf[qt][st] = *(const bf16x8*)(Qh + (size_t)(wv*32 + qt*16 + q4)*EH + st*32 + g*8);

  stage(0, 0);

  const f32x4 Z4 = {0.f, 0.f, 0.f, 0.f};
  f32x4 oacc[4][2];
  #pragma unroll
  for (int a=0;a<4;a++)
    #pragma unroll
    for (int b2=0;b2<2;b2++)
      #pragma unroll
      for (int e=0;e<4;e++) oacc[a][b2][e] = 0.f;
  float lsp[2] = {0.f, 0.f};

  __syncthreads();   // Ks[0], Vt[0] ready
  int buf = 0;
  for (int it = 0; it < NIT; ++it) {
    if (it + 1 < NIT) stage(buf ^ 1, it + 1);

    // QK^T: sac[kvt][qt], row = kv = kvt*16+g*4+reg, col = q = qt*16+q4
    f32x4 sac[2][2];
    __builtin_amdgcn_s_setprio(1);
    #pragma unroll
    for (int kvt=0; kvt<2; ++kvt) {
      int row = kvt*16 + q4;
      int S = (row ^ (row >> 3)) & 7;
      bf16x8 kf0 = *(const bf16x8*)(&Ks[buf][row][(g ^ S)*8]);
      sac[kvt][0] = __builtin_amdgcn_mfma_f32_16x16x32_bf16(kf0, qf[0][0], Z4, 0,0,0);
      sac[kvt][1] = __builtin_amdgcn_mfma_f32_16x16x32_bf16(kf0, qf[1][0], Z4, 0,0,0);
    }
    #pragma unroll
    for (int kvt=0; kvt<2; ++kvt) {
      int row = kvt*16 + q4;
      int S = (row ^ (row >> 3)) & 7;
      bf16x8 kf1 = *(const bf16x8*)(&Ks[buf][row][((4 + g) ^ S)*8]);
      sac[kvt][0] = __builtin_amdgcn_mfma_f32_16x16x32_bf16(kf1, qf[0][1], sac[kvt][0], 0,0,0);
      sac[kvt][1] = __builtin_amdgcn_mfma_f32_16x16x32_bf16(kf1, qf[1][1], sac[kvt][1], 0,0,0);
    }
    __builtin_amdgcn_s_setprio(0);

    // p = exp2(s) -> in-register 16x16x16 B-frags; per-lane ls partials
    s16x4 pk[2][2];   // [qt][kvt]
    #pragma unroll
    for (int qt=0; qt<2; ++qt) {
      #pragma unroll
      for (int kvt=0; kvt<2; ++kvt) {
        float p0 = __builtin_amdgcn_exp2f(sac[kvt][qt][0]);
        float p1 = __builtin_amdgcn_exp2f(sac[kvt][qt][1]);
        float p2 = __builtin_amdgcn_exp2f(sac[kvt][qt][2]);
        float p3 = __builtin_amdgcn_exp2f(sac[kvt][qt][3]);
        lsp[qt] += (p0 + p1) + (p2 + p3);
        union { u32x2 u; s16x4 h; } pu;
        pu.u[0] = cvt_pk_bf16(p0, p1);
        pu.u[1] = cvt_pk_bf16(p2, p3);
        pk[qt][kvt] = pu.h;
      }
    }

    // PV: out^T += V^T * P^T, two K=16 steps, P never leaves registers
    __builtin_amdgcn_s_setprio(1);
    #pragma unroll
    for (int et=0; et<4; ++et) {
      int row = et*16 + q4;
      int s2 = (row ^ (row >> 3)) & 3;
      union { u16x8 w; s16x4 h[2]; } vu;
      vu.w = *(const u16x8*)(&Vt[buf][row][(g ^ s2)*8]);
      oacc[et][0] = mfma16(vu.h[0], pk[0][0], oacc[et][0]);
      oacc[et][0] = mfma16(vu.h[1], pk[0][1], oacc[et][0]);
      oacc[et][1] = mfma16(vu.h[0], pk[1][0], oacc[et][1]);
      oacc[et][1] = mfma16(vu.h[1], pk[1][1], oacc[et][1]);
    }
    __builtin_amdgcn_s_setprio(0);

    __syncthreads();   // drain next-tile DMA + guard dbuf
    buf ^= 1;
  }

  // epilogue: reduce ls across lane groups, write partials / output
  #pragma unroll
  for (int qt=0; qt<2; ++qt) {
    float s = lsp[qt];
    s += __shfl_xor(s, 16, 64);
    s += __shfl_xor(s, 32, 64);
    int q = qblk*QBLK + wv*32 + qt*16 + q4;
    if constexpr (NSPLIT == 1) {
      float inv = 1.f / s;
      unsigned short* rowp = aout + (size_t)(batch*LQ + q)*DM + h*EH;
      #pragma unroll
      for (int et=0; et<4; ++et) {
        #pragma unroll
        for (int rg=0; rg<4; rg+=2) {
          int e = et*16 + g*4 + rg;
          *(unsigned int*)(rowp + e) = cvt_pk_bf16(oacc[et][qt][rg] * inv, oacc[et][qt][rg+1] * inv);
        }
      }
    } else {
      size_t r = (size_t)bh * LQ + q;
      unsigned short* od = opart + ((size_t)r*NSPLIT + part) * 64;
      #pragma unroll
      for (int et=0; et<4; ++et) {
        u32x2 wpk;
        wpk[0] = cvt_pk_bf16(oacc[et][qt][0], oacc[et][qt][1]);
        wpk[1] = cvt_pk_bf16(oacc[et][qt][2], oacc[et][qt][3]);
        *(u32x2*)(od + et*16 + g*4) = wpk;
      }
      if (g == 0) lpart[r*NSPLIT + part] = s;
    }
  }
}

// ---------------- combine split-S partials (bf16) -> bf16 AOut ----------------
extern "C" __global__ __launch_bounds__(256) void k_red(
    const unsigned short* __restrict__ op, const float* __restrict__ lp,
    unsigned short* __restrict__ aout) {
  int t = threadIdx.x;
  int r = blockIdx.x * 16 + (t >> 4);
  int e0 = (t & 15) * 4;
  float acc0 = 0.f, acc1 = 0.f, acc2 = 0.f, acc3 = 0.f, ls = 0.f;
  #pragma unroll
  for (int qq = 0; qq < 4; ++qq) {
    u32x2 wv = *(const u32x2*)(op + ((size_t)r*4 + qq)*64 + e0);
    acc0 += bf2f((unsigned short)(wv[0] & 0xFFFF));
    acc1 += bf2f((unsigned short)(wv[0] >> 16));
    acc2 += bf2f((unsigned short)(wv[1] & 0xFFFF));
    acc3 += bf2f((unsigned short)(wv[1] >> 16));
    ls += lp[(size_t)r*4 + qq];
  }
  float inv = 1.f / ls;
  int bh = r >> 11, q = r & 2047, batch = bh >> 3, h = bh & 7;
  unsigned short* dst = aout + (size_t)(batch*LQ + q)*DM + h*EH + e0;
  u32x2 w;
  w[0] = cvt_pk_bf16(acc0 * inv, acc1 * inv);
  w[1] = cvt_pk_bf16(acc2 * inv, acc3 * inv);
  *(u32x2*)dst = w;
}

// ---------------- output projection GEMM -> f32 ----------------
extern "C" __global__ __launch_bounds__(256) void k_gemm_out(
    const unsigned short* __restrict__ A, const unsigned short* __restrict__ WT,
    const float* __restrict__ bo, float* __restrict__ out) {
  const unsigned short* Bt = WT + (size_t)3 * DM * DM;

  __shared__ unsigned short As[2][128][32];
  __shared__ unsigned short Bs[2][128][32];

  int m0 = blockIdx.y * 128;
  int n0 = blockIdx.x * 128;
  int t = threadIdx.x;
  int lane = t & 63;
  int w = t >> 6;
  int wr = w >> 1, wc = w & 1;
  int g = lane >> 4, r15 = lane & 15;

  f32x4 acc[4][4];
  #pragma unroll
  for (int i=0;i<4;i++)
    #pragma unroll
    for (int j=0;j<4;j++)
      #pragma unroll
      for (int e=0;e<4;e++) acc[i][j][e] = 0.f;

  auto stage = [&](int bb, int kt) {
    int k0 = kt * 32;
    int sblk = (t & 3) ^ ((t >> 3) & 3);
    #pragma unroll
    for (int j=0;j<2;j++) {
      int o = t*16 + j*4096;
      int row = o >> 6;
      gload16(A  + (size_t)(m0+row)*DM + k0 + sblk*8, (char*)(&As[bb][0][0]) + o);
      gload16(Bt + (size_t)(n0+row)*DM + k0 + sblk*8, (char*)(&Bs[bb][0][0]) + o);
    }
  };

  stage(0, 0);
  __syncthreads();
  int buf = 0;
  for (int kt = 0; kt < DM/32; ++kt) {
    if (kt + 1 < DM/32) stage(buf ^ 1, kt + 1);
    bf16x8 af[4], bfr[4];
    #pragma unroll
    for (int mi=0;mi<4;mi++) {
      int row = wr*64 + mi*16 + r15;
      int blk = g ^ ((row >> 1) & 3);
      af[mi] = *(const bf16x8*)(&As[buf][row][blk*8]);
    }
    #pragma unroll
    for (int ni=0;ni<4;ni++) {
      int row = wc*64 + ni*16 + r15;
      int blk = g ^ ((row >> 1) & 3);
      bfr[ni] = *(const bf16x8*)(&Bs[buf][row][blk*8]);
    }
    #pragma unroll
    for (int mi=0;mi<4;mi++)
      #pragma unroll
      for (int ni=0;ni<4;ni++)
        acc[mi][ni] = __builtin_amdgcn_mfma_f32_16x16x32_bf16(af[mi], bfr[ni], acc[mi][ni], 0, 0, 0);
    __syncthreads();
    buf ^= 1;
  }
  #pragma unroll
  for (int ni=0;ni<4;ni++) {
    int n = n0 + wc*64 + ni*16 + r15;
    float bia = bo[n];
    #pragma unroll
    for (int mi=0;mi<4;mi++) {
      #pragma unroll
      for (int rg=0;rg<4;rg++) {
        int m = m0 + wr*64 + mi*16 + g*4 + rg;
        out[(size_t)m*DM + n] = acc[mi][ni][rg] + bia;
      }
    }
  }
}

extern "C" void kernel_launch(void* const* d_in, const int* in_sizes, int n_in,
                              void* d_out, int out_size, void* d_ws, size_t ws_size,
                              hipStream_t stream) {
  const float* queries = (const float*)d_in[0];
  const float* keys    = (const float*)d_in[1];
  const float* values  = (const float*)d_in[2];
  const float* tau     = (const float*)d_in[3];
  // d_in[4] = delta : cancels in softmax -> unused
  const float* Wq = (const float*)d_in[5];
  const float* bq = (const float*)d_in[6];
  const float* Wk = (const float*)d_in[7];
  const float* bk = (const float*)d_in[8];
  const float* Wv = (const float*)d_in[9];
  const float* bv = (const float*)d_in[10];
  const float* Wo = (const float*)d_in[11];
  const float* bo = (const float*)d_in[12];
  float* out = (float*)d_out;

  char* ws = (char*)d_ws;
  unsigned short* WT   = (unsigned short*)(ws);                  // 2 MB  @0
  unsigned short* VTg  = (unsigned short*)(ws + (2u  << 20));    // 8 MB  @2
  unsigned short* AOut = (unsigned short*)(ws + (10u << 20));    // 8 MB  @10
  unsigned short* QKV  = (unsigned short*)(ws + (26u << 20));    // 24 MB @26
  unsigned short* Opart= (unsigned short*)(ws + (50u << 20));    // 33.6 MB @50 (bf16)
  float*          Lpart= (float*)(ws + (84u << 20));             // 1 MB  @84

  k_cast_wt <<<dim3(8, 8, 4), dim3(256), 0, stream>>>(Wq, Wk, Wv, Wo, WT);
  k_gemm_qkv<<<dim3(768), dim3(256), 0, stream>>>(queries, keys, values, WT,
                                                  bq, bk, bv, tau, QKV);
  k_vt      <<<dim3(32, 32), dim3(256), 0, stream>>>(QKV, VTg);

  if (ws_size >= ((size_t)85u << 20)) {
    k_flash<4><<<dim3(2048), dim3(256), 0, stream>>>(QKV, VTg, AOut, Opart, Lpart);
    k_red     <<<dim3(4096), dim3(256), 0, stream>>>(Opart, Lpart, AOut);
  } else {
    k_flash<1><<<dim3(512), dim3(256), 0, stream>>>(QKV, VTg, AOut, Opart, Lpart);
  }
  k_gemm_out<<<dim3(4, 64), dim3(256), 0, stream>>>(AOut, WT, bo, out);
}